// Round 1
// baseline (1320.690 us; speedup 1.0000x reference)
//
#include <hip/hip_runtime.h>
#include <hip/hip_bf16.h>

#define NN 50000      // nodes
#define RR 47         // relations
#define ED 1600       // emb dim (K)
#define WS 16         // weights size (layer1 out)
#define NC 50         // classes
#define NB 40         // bases
#define NE 1600000    // edges
#define WJ (RR*WS)    // 752 = layer1 fused output width
#define WJP 768       // WJ padded to 128 multiple

#define GEMM_NBLK 2346   // 391 m-blocks * 6 n-blocks
#define SCAN_B 1024
#define SCAN_NBLK ((NN + SCAN_B - 1) / SCAN_B)   // 49
#define L2ROWS 16

typedef unsigned short ushort_t;
typedef short s16x8 __attribute__((ext_vector_type(8)));
typedef float f32x4 __attribute__((ext_vector_type(4)));

__device__ __forceinline__ ushort_t f2bf(float f) {
    __hip_bfloat16 h = __float2bfloat16(f);
    ushort_t u;
    __builtin_memcpy(&u, &h, 2);
    return u;
}
__device__ __forceinline__ float bf2f(ushort_t u) {
    unsigned v = ((unsigned)u) << 16;
    float f;
    __builtin_memcpy(&f, &v, 4);
    return f;
}

__device__ __forceinline__ void async_copy16(const ushort_t* g, ushort_t* l) {
    __builtin_amdgcn_global_load_lds(
        (const __attribute__((address_space(1))) unsigned int*)g,
        (__attribute__((address_space(3))) unsigned int*)l,
        16, 0, 0);
}

// ---------------- cast X (fp32) -> bf16, 4 elems/thread ----------------
__global__ void cast_kernel(const float* __restrict__ X, ushort_t* __restrict__ A) {
    int idx = blockIdx.x * blockDim.x + threadIdx.x;   // float4 index
    if (idx >= (NN * ED) / 4) return;
    float4 v = ((const float4*)X)[idx];
    ushort_t* p = &A[idx * 4];
    p[0] = f2bf(v.x); p[1] = f2bf(v.y); p[2] = f2bf(v.z); p[3] = f2bf(v.w);
}

// ---------------- counting: cnt[col] += 1 ----------------
__global__ void count_kernel(const int* __restrict__ cols, float* __restrict__ cnt) {
    int e = blockIdx.x * blockDim.x + threadIdx.x;
    if (e < NE) atomicAdd(&cnt[cols[e]], 1.0f);
}

// ---------------- WbigB[j][i] = sum_b comps1[r,b]*bases1[b,i,o] (bf16, B^T, padded) ----------------
__global__ void wbigbt_kernel(const float* __restrict__ comps1, const float* __restrict__ bases1,
                              ushort_t* __restrict__ WbigB) {
    int idx = blockIdx.x * blockDim.x + threadIdx.x;   // j*ED + i
    if (idx >= WJP * ED) return;
    int j = idx / ED;
    int i = idx - j * ED;
    float s = 0.f;
    if (j < WJ) {
        int r = j >> 4;
        int o = j & 15;
#pragma unroll
        for (int b = 0; b < NB; ++b)
            s += comps1[r * NB + b] * bases1[(b * ED + i) * WS + o];
    }
    WbigB[idx] = f2bf(s);
}

// ---------------- MFMA bf16 GEMM: C[M,752] = A[M,1600] @ B^T, B:(768,1600) ----------------
// 1D grid, n-inner ordering + bijective XCD swizzle (T1): co-resident blocks on an
// XCD share the 409 KB A-panel -> A fetched ~once from HBM instead of ~3x.
__global__ __launch_bounds__(256) void mfma_gemm_kernel(const ushort_t* __restrict__ A,
                                                        const ushort_t* __restrict__ B,
                                                        ushort_t* __restrict__ C) {
    __shared__ ushort_t Abuf[128 * 32];   // 8 KB
    __shared__ ushort_t Bbuf[128 * 32];   // 8 KB

    // bijective XCD swizzle (m204 form): nwg=2346, q=293, r=2
    const int bid = blockIdx.x;
    const int q = GEMM_NBLK / 8, rm = GEMM_NBLK % 8;
    const int xcd = bid & 7, loc = bid >> 3;
    const int sbid = (xcd < rm ? xcd * (q + 1) : rm * (q + 1) + (xcd - rm) * q) + loc;
    const int mb = sbid / 6;          // n fastest: 6 consecutive sbids share A-panel
    const int nb = sbid - mb * 6;

    const int t = threadIdx.x;
    const int lane = t & 63;
    const int wave = t >> 6;
    const int m0 = mb * 128;
    const int n0 = nb * 128;
    const int wm = (wave & 1) * 64;
    const int wn = (wave >> 1) * 64;

    const int arow0 = t >> 2,        akp0 = (t & 3) * 8;
    const int arow1 = (t + 256) >> 2, akp1 = ((t + 256) & 3) * 8;
    int gm0 = m0 + arow0; if (gm0 >= NN) gm0 = NN - 1;
    int gm1 = m0 + arow1; if (gm1 >= NN) gm1 = NN - 1;
    const ushort_t* ap0 = &A[(size_t)gm0 * ED + akp0];
    const ushort_t* ap1 = &A[(size_t)gm1 * ED + akp1];
    const ushort_t* bp0 = &B[(size_t)(n0 + arow0) * ED + akp0];
    const ushort_t* bp1 = &B[(size_t)(n0 + arow1) * ED + akp1];

    f32x4 acc[4][4];
#pragma unroll
    for (int i = 0; i < 4; ++i)
#pragma unroll
        for (int j = 0; j < 4; ++j) acc[i][j] = (f32x4){0.f, 0.f, 0.f, 0.f};

    const int frow = lane & 15;
    const int fk = (lane >> 4) * 8;

    for (int k0 = 0; k0 < ED; k0 += 32) {
        async_copy16(ap0 + k0, &Abuf[t * 8]);
        async_copy16(ap1 + k0, &Abuf[(t + 256) * 8]);
        async_copy16(bp0 + k0, &Bbuf[t * 8]);
        async_copy16(bp1 + k0, &Bbuf[(t + 256) * 8]);
        __syncthreads();

        s16x8 af[4], bf[4];
#pragma unroll
        for (int mt = 0; mt < 4; ++mt)
            af[mt] = *(const s16x8*)&Abuf[(wm + mt * 16 + frow) * 32 + fk];
#pragma unroll
        for (int nt = 0; nt < 4; ++nt)
            bf[nt] = *(const s16x8*)&Bbuf[(wn + nt * 16 + frow) * 32 + fk];
#pragma unroll
        for (int mt = 0; mt < 4; ++mt)
#pragma unroll
            for (int nt = 0; nt < 4; ++nt)
                acc[mt][nt] = __builtin_amdgcn_mfma_f32_16x16x32_bf16(af[mt], bf[nt], acc[mt][nt], 0, 0, 0);
        __syncthreads();
    }

    const int cm = (lane >> 4) * 4;
    const int cn = lane & 15;
#pragma unroll
    for (int mt = 0; mt < 4; ++mt) {
#pragma unroll
        for (int i = 0; i < 4; ++i) {
            int gm = m0 + wm + mt * 16 + cm + i;
            if (gm >= NN) continue;
#pragma unroll
            for (int nt = 0; nt < 4; ++nt) {
                int gn = n0 + wn + nt * 16 + cn;
                if (gn < WJ) C[(size_t)gm * WJ + gn] = f2bf(acc[mt][nt][i]);
            }
        }
    }
}

// ================= CSR build over rows =================
__global__ void hist_kernel(const int* __restrict__ rows, int* __restrict__ rcnt) {
    int e = blockIdx.x * blockDim.x + threadIdx.x;
    if (e < NE) atomicAdd(&rcnt[rows[e]], 1);
}

// per-chunk exclusive scan (Hillis-Steele, double-buffer LDS) + chunk totals
__global__ __launch_bounds__(SCAN_B) void scan1_kernel(const int* __restrict__ rcnt,
                                                       int* __restrict__ ptr,
                                                       int* __restrict__ bsum) {
    __shared__ int buf[2][SCAN_B];
    int t = threadIdx.x, base = blockIdx.x * SCAN_B;
    int v = (base + t < NN) ? rcnt[base + t] : 0;
    buf[0][t] = v;
    __syncthreads();
    int src = 0;
    for (int off = 1; off < SCAN_B; off <<= 1) {
        int x = buf[src][t];
        if (t >= off) x += buf[src][t - off];
        buf[src ^ 1][t] = x;
        src ^= 1;
        __syncthreads();
    }
    int incl = buf[src][t];
    if (base + t < NN) ptr[base + t] = incl - v;    // chunk-exclusive
    if (t == SCAN_B - 1) bsum[blockIdx.x] = incl;   // chunk total
}

// serial scan of 49 chunk totals (in place -> exclusive offsets); ptr[NN] = NE
__global__ void scan2_kernel(int* __restrict__ bsum, int* __restrict__ ptr) {
    if (threadIdx.x == 0 && blockIdx.x == 0) {
        int run = 0;
        for (int i = 0; i < SCAN_NBLK; ++i) { int v = bsum[i]; bsum[i] = run; run += v; }
        ptr[NN] = run;
    }
}

__global__ void scan3_kernel(const int* __restrict__ bsum, int* __restrict__ ptr) {
    int idx = blockIdx.x * blockDim.x + threadIdx.x;
    if (idx < NN) ptr[idx] += bsum[idx >> 10];
}

// scatter edges into row-grouped order; precompute per-edge val = 1/cnt[col]
__global__ void scatter_kernel(const int* __restrict__ rows, const int* __restrict__ cols,
                               const float* __restrict__ cnt, const int* __restrict__ ptr,
                               int* __restrict__ fill, int* __restrict__ ecol,
                               float* __restrict__ eval) {
    int e = blockIdx.x * blockDim.x + threadIdx.x;
    if (e >= NE) return;
    int rw = rows[e];
    int pos = ptr[rw] + atomicAdd(&fill[rw], 1);
    int c = cols[e];
    ecol[pos] = c;
    eval[pos] = 1.0f / cnt[c];
}

// ---------------- spmm1 over CSR: h1[m][o] = relu(bias1[o] + sum_e v*hrel[n][r*16+o]) ----
// one wave per row: 4 edges x 16 outputs per iteration, shfl reduce, no atomics.
__global__ __launch_bounds__(256) void spmm1_csr_kernel(const int* __restrict__ ptr,
        const int* __restrict__ ecol, const float* __restrict__ eval,
        const ushort_t* __restrict__ hrel, const float* __restrict__ bias1,
        float* __restrict__ h1) {
    int t = threadIdx.x;
    int wave = t >> 6, lane = t & 63;
    int m = blockIdx.x * 4 + wave;               // NN divisible by 4
    int start = ptr[m], end = ptr[m + 1];
    int o = lane & 15, sub = lane >> 4;
    float acc = 0.f;
    for (int e0 = start; e0 < end; e0 += 4) {
        int e = e0 + sub;
        if (e < end) {
            int col = ecol[e];
            float v = eval[e];
            int r = col / NN;
            int n = col - r * NN;
            acc += v * bf2f(hrel[(size_t)n * WJ + r * WS + o]);
        }
    }
    acc += __shfl_xor(acc, 16);
    acc += __shfl_xor(acc, 32);
    if (lane < 16) {
        float hv = acc + bias1[o];
        h1[m * WS + o] = hv > 0.f ? hv : 0.f;
    }
}

// ---------------- w2p[k][c] (k=r*16+o, c padded to 64) = sum_b comps2[r,b]*bases2[b,o,c] ----------------
__global__ void w2p_kernel(const float* __restrict__ comps2, const float* __restrict__ bases2,
                           float* __restrict__ w2p) {
    int idx = blockIdx.x * blockDim.x + threadIdx.x;   // k*64 + c
    if (idx >= WJ * 64) return;
    int k = idx >> 6;
    int c = idx & 63;
    float s = 0.f;
    if (c < NC) {
        int r = k >> 4;
        int o = k & 15;
#pragma unroll
        for (int b = 0; b < NB; ++b)
            s += comps2[r * NB + b] * bases2[(b * WS + o) * NC + c];
    }
    w2p[idx] = s;
}

// ---------------- fused layer 2: G-tile (16 rows x 752) lives in LDS only ----------------
// phase 1: zero; phase 2: CSR edge accumulate via ds_add_f32; phase 3: tile GEMM vs w2p.
__global__ __launch_bounds__(256) void layer2_kernel(const int* __restrict__ ptr,
        const int* __restrict__ ecol, const float* __restrict__ eval,
        const float* __restrict__ h1, const float* __restrict__ w2p,
        const float* __restrict__ bias2, float* __restrict__ out) {
    __shared__ float gt[L2ROWS][WJ];    // 48128 B
    __shared__ float Bs[16][68];        //  4352 B  -> 52.5 KB total, 3 blocks/CU

    int t = threadIdx.x;
    int m0 = blockIdx.x * L2ROWS;

    for (int i = t; i < L2ROWS * WJ; i += 256) ((float*)gt)[i] = 0.f;
    __syncthreads();

    int wave = t >> 6, lane = t & 63;
    int o = lane & 15, sub = lane >> 4;
    for (int lr = wave * 4; lr < wave * 4 + 4; ++lr) {   // each wave owns 4 rows
        int m = m0 + lr;
        if (m >= NN) break;
        int start = ptr[m], end = ptr[m + 1];
        for (int e0 = start; e0 < end; e0 += 4) {
            int e = e0 + sub;
            if (e < end) {
                int col = ecol[e];
                float v = eval[e];
                int r = col / NN;
                int n = col - r * NN;
                atomicAdd(&gt[lr][r * WS + o], v * h1[n * WS + o]);
            }
        }
    }
    __syncthreads();

    int i = t >> 4, tx = t & 15;
    float acc[4] = {0.f, 0.f, 0.f, 0.f};
    for (int k0 = 0; k0 < WJ; k0 += 16) {
        *(float4*)&Bs[t >> 4][(t & 15) * 4] =
            *(const float4*)&w2p[(k0 + (t >> 4)) * 64 + (t & 15) * 4];
        __syncthreads();
#pragma unroll
        for (int k = 0; k < 16; ++k) {
            float a = gt[i][k0 + k];                       // broadcast within 16-lane group
            float4 b = *(const float4*)&Bs[k][tx * 4];
            acc[0] += a * b.x; acc[1] += a * b.y; acc[2] += a * b.z; acc[3] += a * b.w;
        }
        __syncthreads();
    }
    int m = m0 + i;
    if (m < NN) {
#pragma unroll
        for (int j = 0; j < 4; ++j) {
            int c = tx * 4 + j;
            if (c < NC) out[m * NC + c] = acc[j] + bias2[c];
        }
    }
}

extern "C" void kernel_launch(void* const* d_in, const int* in_sizes, int n_in,
                              void* d_out, int out_size, void* d_ws, size_t ws_size,
                              hipStream_t stream) {
    const float* X      = (const float*)d_in[0];   // (NN, ED)
    const float* comps1 = (const float*)d_in[1];   // (RR, NB)
    const float* bases1 = (const float*)d_in[2];   // (NB, ED, WS)
    const float* comps2 = (const float*)d_in[3];   // (RR, NB)
    const float* bases2 = (const float*)d_in[4];   // (NB, WS, NC)
    const float* bias1  = (const float*)d_in[5];   // (WS,)
    const float* bias2  = (const float*)d_in[6];   // (NC,)
    const int*   rows   = (const int*)d_in[7];     // (NE,)
    const int*   cols   = (const int*)d_in[8];     // (NE,)
    float* out = (float*)d_out;                    // (NN, NC)

    char* ws = (char*)d_ws;
    // workspace layout (64-aligned), 250.45 MB total (same footprint as before).
    // CSR arrays alias Abf: Abf is dead after mfma_gemm; all CSR kernels launch after.
    float*    cnt    = (float*)   (ws + 0);            // RR*NN*4  =   9,400,000 B
    ushort_t* Abf    = (ushort_t*)(ws + 9400064);      // NN*ED*2  = 160,000,000 B
    int*      rowptr = (int*)     (ws + 9400064);      // (NN+1)*4 (alias Abf)
    int*      rcnt   = (int*)     (ws + 9600128);      // NN*4     (alias Abf)
    int*      fill   = (int*)     (ws + 9800192);      // NN*4     (alias Abf)
    int*      bsum   = (int*)     (ws + 10000256);     // 49*4     (alias Abf)
    int*      ecol   = (int*)     (ws + 10000512);     // NE*4     (alias Abf)
    float*    eval   = (float*)   (ws + 16400512);     // NE*4     (alias Abf, ends 22.8 MB)
    ushort_t* WbigB  = (ushort_t*)(ws + 169400064);    // WJP*ED*2 =   2,457,600 B
    ushort_t* hrel   = (ushort_t*)(ws + 171857664);    // NN*WJ*2  =  75,200,000 B
    float*    h1     = (float*)   (ws + 247057664);    // NN*WS*4  =   3,200,000 B
    float*    w2p    = (float*)   (ws + 250257664);    // WJ*64*4  =     192,512 B

    hipMemsetAsync(cnt, 0, (size_t)RR * NN * 4, stream);

    cast_kernel<<<(NN * ED / 4 + 255) / 256, 256, 0, stream>>>(X, Abf);
    count_kernel<<<(NE + 255) / 256, 256, 0, stream>>>(cols, cnt);
    wbigbt_kernel<<<(WJP * ED + 255) / 256, 256, 0, stream>>>(comps1, bases1, WbigB);

    mfma_gemm_kernel<<<GEMM_NBLK, 256, 0, stream>>>(Abf, WbigB, hrel);

    // ---- CSR build (aliases Abf: must stay after mfma_gemm in stream order) ----
    hipMemsetAsync(rcnt, 0, (size_t)NN * 4, stream);
    hipMemsetAsync(fill, 0, (size_t)NN * 4, stream);
    hist_kernel<<<(NE + 255) / 256, 256, 0, stream>>>(rows, rcnt);
    scan1_kernel<<<SCAN_NBLK, SCAN_B, 0, stream>>>(rcnt, rowptr, bsum);
    scan2_kernel<<<1, 64, 0, stream>>>(bsum, rowptr);
    scan3_kernel<<<(NN + 255) / 256, 256, 0, stream>>>(bsum, rowptr);
    scatter_kernel<<<(NE + 255) / 256, 256, 0, stream>>>(rows, cols, cnt, rowptr, fill, ecol, eval);

    // ---- layer 1 aggregate (gather, fused bias+relu) ----
    spmm1_csr_kernel<<<NN / 4, 256, 0, stream>>>(rowptr, ecol, eval, hrel, bias1, h1);

    // ---- layer 2 (fused aggregate + GEMM; G never materialized) ----
    w2p_kernel<<<(WJ * 64 + 255) / 256, 256, 0, stream>>>(comps2, bases2, w2p);
    layer2_kernel<<<(NN + L2ROWS - 1) / L2ROWS, 256, 0, stream>>>(rowptr, ecol, eval, h1, w2p, bias2, out);
}

// Round 2
// 1188.609 us; speedup vs baseline: 1.1111x; 1.1111x over previous
//
#include <hip/hip_runtime.h>
#include <hip/hip_bf16.h>

#define NN 50000      // nodes
#define RR 47         // relations
#define ED 1600       // emb dim (K)
#define WS 16         // weights size (layer1 out)
#define NC 50         // classes
#define NB 40         // bases
#define NE 1600000    // edges
#define WJ (RR*WS)    // 752 = layer1 fused output width
#define WJP 768       // WJ padded to 128 multiple

#define GEMM_NBLK 2346   // 391 m-blocks * 6 n-blocks
#define SCAN_B 1024
#define SCAN_NBLK ((NN + SCAN_B - 1) / SCAN_B)   // 49
#define L2ROWS 16
#define GTS 772          // gt LDS stride (f32): %32==4 -> 2-way (free), 16B aligned

typedef unsigned short ushort_t;
typedef short s16x8 __attribute__((ext_vector_type(8)));
typedef short s16x4 __attribute__((ext_vector_type(4)));
typedef float f32x4 __attribute__((ext_vector_type(4)));

__device__ __forceinline__ ushort_t f2bf(float f) {
    __hip_bfloat16 h = __float2bfloat16(f);
    ushort_t u;
    __builtin_memcpy(&u, &h, 2);
    return u;
}
__device__ __forceinline__ float bf2f(ushort_t u) {
    unsigned v = ((unsigned)u) << 16;
    float f;
    __builtin_memcpy(&f, &v, 4);
    return f;
}

__device__ __forceinline__ void async_copy16(const ushort_t* g, ushort_t* l) {
    __builtin_amdgcn_global_load_lds(
        (const __attribute__((address_space(1))) unsigned int*)g,
        (__attribute__((address_space(3))) unsigned int*)l,
        16, 0, 0);
}

// ---------------- cast X (fp32) -> bf16, 4 elems/thread ----------------
__global__ void cast_kernel(const float* __restrict__ X, ushort_t* __restrict__ A) {
    int idx = blockIdx.x * blockDim.x + threadIdx.x;   // float4 index
    if (idx >= (NN * ED) / 4) return;
    float4 v = ((const float4*)X)[idx];
    ushort_t* p = &A[idx * 4];
    p[0] = f2bf(v.x); p[1] = f2bf(v.y); p[2] = f2bf(v.z); p[3] = f2bf(v.w);
}

// ---------------- counting: cnt[col] += 1 ----------------
__global__ void count_kernel(const int* __restrict__ cols, float* __restrict__ cnt) {
    int e = blockIdx.x * blockDim.x + threadIdx.x;
    if (e < NE) atomicAdd(&cnt[cols[e]], 1.0f);
}

// ---------------- WbigB[j][i] = sum_b comps1[r,b]*bases1[b,i,o] (bf16, B^T, padded) ----------------
__global__ void wbigbt_kernel(const float* __restrict__ comps1, const float* __restrict__ bases1,
                              ushort_t* __restrict__ WbigB) {
    int idx = blockIdx.x * blockDim.x + threadIdx.x;   // j*ED + i
    if (idx >= WJP * ED) return;
    int j = idx / ED;
    int i = idx - j * ED;
    float s = 0.f;
    if (j < WJ) {
        int r = j >> 4;
        int o = j & 15;
#pragma unroll
        for (int b = 0; b < NB; ++b)
            s += comps1[r * NB + b] * bases1[(b * ED + i) * WS + o];
    }
    WbigB[idx] = f2bf(s);
}

// ---------------- MFMA bf16 GEMM: C[M,752] = A[M,1600] @ B^T, B:(768,1600) ----------------
// 1D grid, n-inner ordering + bijective XCD swizzle (T1).
__global__ __launch_bounds__(256) void mfma_gemm_kernel(const ushort_t* __restrict__ A,
                                                        const ushort_t* __restrict__ B,
                                                        ushort_t* __restrict__ C) {
    __shared__ ushort_t Abuf[128 * 32];   // 8 KB
    __shared__ ushort_t Bbuf[128 * 32];   // 8 KB

    // bijective XCD swizzle (m204 form): nwg=2346, q=293, r=2
    const int bid = blockIdx.x;
    const int q = GEMM_NBLK / 8, rm = GEMM_NBLK % 8;
    const int xcd = bid & 7, loc = bid >> 3;
    const int sbid = (xcd < rm ? xcd * (q + 1) : rm * (q + 1) + (xcd - rm) * q) + loc;
    const int mb = sbid / 6;          // n fastest: 6 consecutive sbids share A-panel
    const int nb = sbid - mb * 6;

    const int t = threadIdx.x;
    const int lane = t & 63;
    const int wave = t >> 6;
    const int m0 = mb * 128;
    const int n0 = nb * 128;
    const int wm = (wave & 1) * 64;
    const int wn = (wave >> 1) * 64;

    const int arow0 = t >> 2,        akp0 = (t & 3) * 8;
    const int arow1 = (t + 256) >> 2, akp1 = ((t + 256) & 3) * 8;
    int gm0 = m0 + arow0; if (gm0 >= NN) gm0 = NN - 1;
    int gm1 = m0 + arow1; if (gm1 >= NN) gm1 = NN - 1;
    const ushort_t* ap0 = &A[(size_t)gm0 * ED + akp0];
    const ushort_t* ap1 = &A[(size_t)gm1 * ED + akp1];
    const ushort_t* bp0 = &B[(size_t)(n0 + arow0) * ED + akp0];
    const ushort_t* bp1 = &B[(size_t)(n0 + arow1) * ED + akp1];

    f32x4 acc[4][4];
#pragma unroll
    for (int i = 0; i < 4; ++i)
#pragma unroll
        for (int j = 0; j < 4; ++j) acc[i][j] = (f32x4){0.f, 0.f, 0.f, 0.f};

    const int frow = lane & 15;
    const int fk = (lane >> 4) * 8;

    for (int k0 = 0; k0 < ED; k0 += 32) {
        async_copy16(ap0 + k0, &Abuf[t * 8]);
        async_copy16(ap1 + k0, &Abuf[(t + 256) * 8]);
        async_copy16(bp0 + k0, &Bbuf[t * 8]);
        async_copy16(bp1 + k0, &Bbuf[(t + 256) * 8]);
        __syncthreads();

        s16x8 af[4], bf[4];
#pragma unroll
        for (int mt = 0; mt < 4; ++mt)
            af[mt] = *(const s16x8*)&Abuf[(wm + mt * 16 + frow) * 32 + fk];
#pragma unroll
        for (int nt = 0; nt < 4; ++nt)
            bf[nt] = *(const s16x8*)&Bbuf[(wn + nt * 16 + frow) * 32 + fk];
#pragma unroll
        for (int mt = 0; mt < 4; ++mt)
#pragma unroll
            for (int nt = 0; nt < 4; ++nt)
                acc[mt][nt] = __builtin_amdgcn_mfma_f32_16x16x32_bf16(af[mt], bf[nt], acc[mt][nt], 0, 0, 0);
        __syncthreads();
    }

    const int cm = (lane >> 4) * 4;
    const int cn = lane & 15;
#pragma unroll
    for (int mt = 0; mt < 4; ++mt) {
#pragma unroll
        for (int i = 0; i < 4; ++i) {
            int gm = m0 + wm + mt * 16 + cm + i;
            if (gm >= NN) continue;
#pragma unroll
            for (int nt = 0; nt < 4; ++nt) {
                int gn = n0 + wn + nt * 16 + cn;
                if (gn < WJ) C[(size_t)gm * WJ + gn] = f2bf(acc[mt][nt][i]);
            }
        }
    }
}

// ================= CSR build over rows =================
__global__ void hist_kernel(const int* __restrict__ rows, int* __restrict__ rcnt) {
    int e = blockIdx.x * blockDim.x + threadIdx.x;
    if (e < NE) atomicAdd(&rcnt[rows[e]], 1);
}

__global__ __launch_bounds__(SCAN_B) void scan1_kernel(const int* __restrict__ rcnt,
                                                       int* __restrict__ ptr,
                                                       int* __restrict__ bsum) {
    __shared__ int buf[2][SCAN_B];
    int t = threadIdx.x, base = blockIdx.x * SCAN_B;
    int v = (base + t < NN) ? rcnt[base + t] : 0;
    buf[0][t] = v;
    __syncthreads();
    int src = 0;
    for (int off = 1; off < SCAN_B; off <<= 1) {
        int x = buf[src][t];
        if (t >= off) x += buf[src][t - off];
        buf[src ^ 1][t] = x;
        src ^= 1;
        __syncthreads();
    }
    int incl = buf[src][t];
    if (base + t < NN) ptr[base + t] = incl - v;    // chunk-exclusive
    if (t == SCAN_B - 1) bsum[blockIdx.x] = incl;   // chunk total
}

__global__ void scan2_kernel(int* __restrict__ bsum, int* __restrict__ ptr) {
    if (threadIdx.x == 0 && blockIdx.x == 0) {
        int run = 0;
        for (int i = 0; i < SCAN_NBLK; ++i) { int v = bsum[i]; bsum[i] = run; run += v; }
        ptr[NN] = run;
    }
}

__global__ void scan3_kernel(const int* __restrict__ bsum, int* __restrict__ ptr) {
    int idx = blockIdx.x * blockDim.x + threadIdx.x;
    if (idx < NN) ptr[idx] += bsum[idx >> 10];
}

// scatter edges into row-grouped order; also emit per-edge row (ushort) and val=1/cnt[col]
__global__ void scatter_kernel(const int* __restrict__ rows, const int* __restrict__ cols,
                               const float* __restrict__ cnt, const int* __restrict__ ptr,
                               int* __restrict__ fill, int* __restrict__ ecol,
                               float* __restrict__ eval, ushort_t* __restrict__ erow) {
    int e = blockIdx.x * blockDim.x + threadIdx.x;
    if (e >= NE) return;
    int rw = rows[e];
    int pos = ptr[rw] + atomicAdd(&fill[rw], 1);
    int c = cols[e];
    ecol[pos] = c;
    eval[pos] = 1.0f / cnt[c];
    erow[pos] = (ushort_t)rw;
}

// ---------------- spmm1 over CSR: h1[m][o] = relu(bias1[o] + sum_e v*hrel[n][r*16+o]) ----
// one wave per row: 16 edges x (4 lanes x 4 outs) per iteration, shfl-tree reduce.
__global__ __launch_bounds__(256) void spmm1_csr_kernel(const int* __restrict__ ptr,
        const int* __restrict__ ecol, const float* __restrict__ eval,
        const ushort_t* __restrict__ hrel, const float* __restrict__ bias1,
        float* __restrict__ h1) {
    int t = threadIdx.x;
    int wave = t >> 6, lane = t & 63;
    int m = blockIdx.x * 4 + wave;               // NN divisible by 4
    int start = ptr[m], end = ptr[m + 1];
    int sub = lane >> 2;          // 0..15 edge slot
    int oq = (lane & 3) * 4;      // output quad base
    float acc[4] = {0.f, 0.f, 0.f, 0.f};
    for (int e0 = start; e0 < end; e0 += 16) {
        int e = e0 + sub;
        if (e < end) {
            int col = ecol[e];
            float v = eval[e];
            int r = col / NN;
            int n = col - r * NN;
            s16x4 hv = *(const s16x4*)&hrel[(size_t)n * WJ + r * WS + oq];
#pragma unroll
            for (int j = 0; j < 4; ++j)
                acc[j] += v * bf2f((ushort_t)hv[j]);
        }
    }
#pragma unroll
    for (int d = 4; d <= 32; d <<= 1)
#pragma unroll
        for (int j = 0; j < 4; ++j)
            acc[j] += __shfl_xor(acc[j], d);
    if (lane < 4) {
        float4 hv;
        float* hp = (float*)&hv;
#pragma unroll
        for (int j = 0; j < 4; ++j) {
            float x = acc[j] + bias1[oq + j];
            hp[j] = x > 0.f ? x : 0.f;
        }
        *(float4*)&h1[m * WS + oq] = hv;
    }
}

// ---------------- w2pT[c][k] (bf16, c:64 padded, k:768 padded) = sum_b comps2[r,b]*bases2[b,o,c] ----
__global__ void w2pt_kernel(const float* __restrict__ comps2, const float* __restrict__ bases2,
                            ushort_t* __restrict__ w2pT) {
    int idx = blockIdx.x * blockDim.x + threadIdx.x;   // c*768 + k
    if (idx >= 64 * 768) return;
    int c = idx / 768;
    int k = idx - c * 768;
    float s = 0.f;
    if (c < NC && k < WJ) {
        int r = k >> 4;
        int o = k & 15;
#pragma unroll
        for (int b = 0; b < NB; ++b)
            s += comps2[r * NB + b] * bases2[(b * WS + o) * NC + c];
    }
    w2pT[idx] = f2bf(s);
}

// ---------------- fused layer 2: G-tile (16 rows x 752) in LDS, MFMA for the GEMM phase ----
// phase 1: zero; phase 2: flat CSR edge accumulate via LDS atomics; phase 3: MFMA vs w2pT.
__global__ __launch_bounds__(256) void layer2_kernel(const int* __restrict__ ptr,
        const int* __restrict__ ecol, const float* __restrict__ eval,
        const ushort_t* __restrict__ erow,
        const float* __restrict__ h1, const ushort_t* __restrict__ w2pT,
        const float* __restrict__ bias2, float* __restrict__ out) {
    __shared__ float gt[L2ROWS][GTS];    // 16*772*4 = 49408 B -> 3 blocks/CU

    int t = threadIdx.x;
    int m0 = blockIdx.x * L2ROWS;        // 3125 blocks, NN = 3125*16 exactly

    for (int i = t; i < L2ROWS * GTS; i += 256) ((float*)gt)[i] = 0.f;
    __syncthreads();

    // edge phase: flat over the block's contiguous CSR range, 16 edges in flight
    {
        int estart = ptr[m0];
        int eend = ptr[m0 + L2ROWS];
        int g = t >> 4, o = t & 15;
        for (int e = estart + g; e < eend; e += 16) {
            int col = ecol[e];
            float v = eval[e];
            int lr = (int)erow[e] - m0;
            int r = col / NN;
            int n = col - r * NN;
            atomicAdd(&gt[lr][r * WS + o], v * h1[n * WS + o]);
        }
    }
    __syncthreads();

    // MFMA phase: out[16 x 64] = gt[16 x 768] @ w2pT^T; wave w owns cols w*16..w*16+15
    int wave = t >> 6, lane = t & 63;
    int arow = lane & 15;
    int kx = (lane >> 4) * 8;
    int n0 = wave * 16;
    f32x4 acc = (f32x4){0.f, 0.f, 0.f, 0.f};
    const ushort_t* bbase = &w2pT[(size_t)(n0 + arow) * 768 + kx];
    for (int k0 = 0; k0 < 768; k0 += 32) {
        // A frag: 8 f32 from gt row, convert to bf16 (cols 752..767 are zero pad)
        f32x4 a0 = *(const f32x4*)&gt[arow][k0 + kx];
        f32x4 a1 = *(const f32x4*)&gt[arow][k0 + kx + 4];
        s16x8 af;
        af[0] = (short)f2bf(a0[0]); af[1] = (short)f2bf(a0[1]);
        af[2] = (short)f2bf(a0[2]); af[3] = (short)f2bf(a0[3]);
        af[4] = (short)f2bf(a1[0]); af[5] = (short)f2bf(a1[1]);
        af[6] = (short)f2bf(a1[2]); af[7] = (short)f2bf(a1[3]);
        // B frag: bf16 from global (L2-resident 98 KB)
        s16x8 bf = *(const s16x8*)&bbase[k0];
        acc = __builtin_amdgcn_mfma_f32_16x16x32_bf16(af, bf, acc, 0, 0, 0);
    }
    // C layout: col = lane&15, row = (lane>>4)*4 + i
    int cn = n0 + (lane & 15);
    if (cn < NC) {
        int rbase = (lane >> 4) * 4;
        float b2 = bias2[cn];
#pragma unroll
        for (int i = 0; i < 4; ++i) {
            int m = m0 + rbase + i;
            out[m * NC + cn] = acc[i] + b2;
        }
    }
}

extern "C" void kernel_launch(void* const* d_in, const int* in_sizes, int n_in,
                              void* d_out, int out_size, void* d_ws, size_t ws_size,
                              hipStream_t stream) {
    const float* X      = (const float*)d_in[0];   // (NN, ED)
    const float* comps1 = (const float*)d_in[1];   // (RR, NB)
    const float* bases1 = (const float*)d_in[2];   // (NB, ED, WS)
    const float* comps2 = (const float*)d_in[3];   // (RR, NB)
    const float* bases2 = (const float*)d_in[4];   // (NB, WS, NC)
    const float* bias1  = (const float*)d_in[5];   // (WS,)
    const float* bias2  = (const float*)d_in[6];   // (NC,)
    const int*   rows   = (const int*)d_in[7];     // (NE,)
    const int*   cols   = (const int*)d_in[8];     // (NE,)
    float* out = (float*)d_out;                    // (NN, NC)

    char* ws = (char*)d_ws;
    // workspace layout (64-aligned). CSR arrays alias Abf (dead after mfma_gemm).
    float*    cnt    = (float*)   (ws + 0);            // RR*NN*4  =   9,400,000 B
    ushort_t* Abf    = (ushort_t*)(ws + 9400064);      // NN*ED*2  = 160,000,000 B
    int*      rowptr = (int*)     (ws + 9400064);      // (NN+1)*4 (alias Abf)
    int*      rcnt   = (int*)     (ws + 9600128);      // NN*4     (alias Abf)
    int*      fill   = (int*)     (ws + 9800192);      // NN*4     (alias Abf)
    int*      bsum   = (int*)     (ws + 10000256);     // 49*4     (alias Abf)
    int*      ecol   = (int*)     (ws + 10000512);     // NE*4     (alias Abf)
    float*    eval   = (float*)   (ws + 16400512);     // NE*4     (alias Abf)
    ushort_t* erow   = (ushort_t*)(ws + 22800512);     // NE*2     (alias Abf, ends 26.0 MB)
    ushort_t* WbigB  = (ushort_t*)(ws + 169400064);    // WJP*ED*2 =   2,457,600 B
    ushort_t* hrel   = (ushort_t*)(ws + 171857664);    // NN*WJ*2  =  75,200,000 B
    float*    h1     = (float*)   (ws + 247057664);    // NN*WS*4  =   3,200,000 B
    ushort_t* w2pT   = (ushort_t*)(ws + 250257664);    // 64*768*2 =      98,304 B

    hipMemsetAsync(cnt, 0, (size_t)RR * NN * 4, stream);

    cast_kernel<<<(NN * ED / 4 + 255) / 256, 256, 0, stream>>>(X, Abf);
    count_kernel<<<(NE + 255) / 256, 256, 0, stream>>>(cols, cnt);
    wbigbt_kernel<<<(WJP * ED + 255) / 256, 256, 0, stream>>>(comps1, bases1, WbigB);

    mfma_gemm_kernel<<<GEMM_NBLK, 256, 0, stream>>>(Abf, WbigB, hrel);

    // ---- CSR build (aliases Abf: must stay after mfma_gemm in stream order) ----
    hipMemsetAsync(rcnt, 0, (size_t)NN * 4, stream);
    hipMemsetAsync(fill, 0, (size_t)NN * 4, stream);
    hist_kernel<<<(NE + 255) / 256, 256, 0, stream>>>(rows, rcnt);
    scan1_kernel<<<SCAN_NBLK, SCAN_B, 0, stream>>>(rcnt, rowptr, bsum);
    scan2_kernel<<<1, 64, 0, stream>>>(bsum, rowptr);
    scan3_kernel<<<(NN + 255) / 256, 256, 0, stream>>>(bsum, rowptr);
    scatter_kernel<<<(NE + 255) / 256, 256, 0, stream>>>(rows, cols, cnt, rowptr, fill, ecol, eval, erow);

    // ---- layer 1 aggregate (gather, fused bias+relu) ----
    spmm1_csr_kernel<<<NN / 4, 256, 0, stream>>>(rowptr, ecol, eval, hrel, bias1, h1);

    // ---- layer 2 (fused aggregate + MFMA GEMM; G never materialized) ----
    w2pt_kernel<<<(64 * 768 + 255) / 256, 256, 0, stream>>>(comps2, bases2, w2pT);
    layer2_kernel<<<NN / L2ROWS, 256, 0, stream>>>(rowptr, ecol, eval, erow, h1, w2pT, bias2, out);
}